// Round 2
// baseline (78.986 us; speedup 1.0000x reference)
//
#include <hip/hip_runtime.h>
#include <math.h>

// B=2048, F=512, K=32, P=3K+1=97
constexpr int Bn = 2048;
constexpr int Fn = 512;
constexpr int Kn = 32;
constexpr int Pn = 3 * Kn + 1;  // 97

// One block per batch row b (512 threads = 8 waves), one thread per feature f.
// ALL 97 parameter loads per thread are coalesced (stride-1 in f across lanes).
// Slope selection uses the monotonicity of c_j = (x > knots_x[j]) to pick
// slope[bin] (last true) and slope[bin+1] (true->false transition) with
// predicated selects -- no data-dependent addressing anywhere.
__global__ __launch_bounds__(Fn) void nsf_kernel(
    const float* __restrict__ x,
    const float* __restrict__ prm,
    const float* __restrict__ x0,
    const float* __restrict__ xf,
    float* __restrict__ y_out,
    float* __restrict__ ld_out)
{
    const int b = blockIdx.x;
    const int f = threadIdx.x;

    const float xv   = x[(size_t)b * Fn + f];
    const float x0v  = x0[f];
    const float span = xf[f] - x0v;

    const float* pb = prm + (size_t)b * Pn * Fn + f;

    // ---- softmax over width/height logits, no max-subtraction (logits ~N(0,1),
    // exp in [e^-6, e^6] -- exact in fp32, and exp fuses into the load loop) ----
    float ew[Kn], eh[Kn];
    float Sw = 0.f, Sh = 0.f;
#pragma unroll
    for (int j = 0; j < Kn; ++j) { float e = __expf(pb[(size_t)j * Fn]);        ew[j] = e; Sw += e; }
#pragma unroll
    for (int j = 0; j < Kn; ++j) { float e = __expf(pb[(size_t)(Kn + j) * Fn]); eh[j] = e; Sh += e; }
    const float invSw = span / Sw;   // widths[j]  = ew[j] * invSw
    const float invSh = span / Sh;   // heights[j] = eh[j] * invSh

    const float* ps = pb + (size_t)(2 * Kn) * Fn;  // slope logit rows 0..32

    // ---- fused cumsum + bin search + gather of w,h,knots,slopes ----
    // c_j monotone non-increasing (knots_x strictly increasing).
    // bin = last j with c'_j, c'_0 forced true (reproduces the clip to [0,K-1]).
    float cumx = 0.f, cumy = 0.f;
    float w_b = 0.f, h_b = 0.f, xk = 0.f, yk = 0.f, s0 = 0.f, s1 = 0.f;
    bool cprev = false;
#pragma unroll
    for (int j = 0; j < Kn; ++j) {
        const float wj  = ew[j] * invSw;
        const float hj  = eh[j] * invSh;
        const float slj = ps[(size_t)j * Fn];          // coalesced slope row j
        const bool  c   = (xv > x0v + cumx) || (j == 0);
        if (c)            { w_b = wj; h_b = hj; xk = cumx; yk = cumy; s0 = slj; }
        if (cprev && !c)  { s1 = slj; }                // fires once: j == bin+1
        cprev = c;
        cumx += wj; cumy += hj;
    }
    {   // epilogue j = Kn: slope row 96; fires iff bin == Kn-1
        const float slj = ps[(size_t)Kn * Fn];
        if (cprev) s1 = slj;
    }
    const float xk_b = x0v + xk;
    const float yk_b = x0v + yk;

    // softplus(s) = max(s,0) + log1p(exp(-|s|))
    const float d_k  = fmaxf(s0, 0.f) + log1pf(__expf(-fabsf(s0)));
    const float d_k1 = fmaxf(s1, 0.f) + log1pf(__expf(-fabsf(s1)));

    // ---- rational-quadratic spline ----
    const float invw = 1.f / w_b;
    const float s    = h_b * invw;
    const float eps  = (xv - xk_b) * invw;
    const float ome  = 1.f - eps;
    const float e1m  = eps * ome;
    const float e2   = eps * eps;
    const float den  = s + (d_k1 + d_k - 2.f * s) * e1m;
    const float invd = 1.f / den;
    const float yv   = yk_b + h_b * (s * e2 + d_k * e1m) * invd;
    const float dy   = s * s * (d_k1 * e2 + 2.f * s * e1m + d_k * ome * ome) * (invd * invd);

    y_out[(size_t)b * Fn + f] = yv;

    // ---- block reduction of log(dy) over F=512 (8 waves) ----
    float ld = __logf(dy);
#pragma unroll
    for (int off = 32; off > 0; off >>= 1)
        ld += __shfl_down(ld, off, 64);

    __shared__ float wsum[Fn / 64];
    const int lane = f & 63;
    const int wv   = f >> 6;
    if (lane == 0) wsum[wv] = ld;
    __syncthreads();
    if (f == 0) {
        float t = 0.f;
#pragma unroll
        for (int i = 0; i < Fn / 64; ++i) t += wsum[i];
        ld_out[b] = t;
    }
}

extern "C" void kernel_launch(void* const* d_in, const int* in_sizes, int n_in,
                              void* d_out, int out_size, void* d_ws, size_t ws_size,
                              hipStream_t stream) {
    const float* x   = (const float*)d_in[0];
    const float* prm = (const float*)d_in[1];
    const float* x0  = (const float*)d_in[2];
    const float* xf  = (const float*)d_in[3];
    float* y  = (float*)d_out;                  // (B, F) flat
    float* ld = y + (size_t)Bn * Fn;            // (B,) appended

    nsf_kernel<<<Bn, Fn, 0, stream>>>(x, prm, x0, xf, y, ld);
}

// Round 3
// 77.386 us; speedup vs baseline: 1.0207x; 1.0207x over previous
//
#include <hip/hip_runtime.h>
#include <math.h>

// B=2048, F=512, K=32, P=3K+1=97
constexpr int Bn = 2048;
constexpr int Fn = 512;
constexpr int Kn = 32;
constexpr int Pn = 3 * Kn + 1;  // 97

// One block per batch row b; 256 threads, each handling TWO features (2t, 2t+1)
// via float2 loads (8 B/lane = 512 B per wave-instruction).
// Slopes are fetched by per-lane gather at the found bin (R1 structure: the
// gather touches only ~87% of slope lines vs 100% for coalesced-all-rows).
__global__ __launch_bounds__(256, 2) void nsf_kernel(
    const float* __restrict__ x,
    const float* __restrict__ prm,
    const float* __restrict__ x0,
    const float* __restrict__ xf,
    float* __restrict__ y_out,
    float* __restrict__ ld_out)
{
    const int b = blockIdx.x;
    const int t = threadIdx.x;           // features fA=2t, fB=2t+1

    const float2 xv2 = ((const float2*)(x + (size_t)b * Fn))[t];
    const float2 x02 = ((const float2*)x0)[t];
    const float2 xf2 = ((const float2*)xf)[t];
    const float spanA = xf2.x - x02.x;
    const float spanB = xf2.y - x02.y;

    const float*  pb  = prm + (size_t)b * Pn * Fn;
    const float2* pb2 = (const float2*)pb + t;       // row stride = Fn/2 float2

    // ---- softmax exps (no max-subtraction: logits ~N(0,1), exact in fp32) ----
    float ewA[Kn], ewB[Kn], ehA[Kn], ehB[Kn];
    float SwA = 0.f, SwB = 0.f, ShA = 0.f, ShB = 0.f;
#pragma unroll
    for (int j = 0; j < Kn; ++j) {
        const float2 v = pb2[(size_t)j * (Fn / 2)];
        const float ea = __expf(v.x), eb = __expf(v.y);
        ewA[j] = ea; ewB[j] = eb; SwA += ea; SwB += eb;
    }
#pragma unroll
    for (int j = 0; j < Kn; ++j) {
        const float2 v = pb2[(size_t)(Kn + j) * (Fn / 2)];
        const float ea = __expf(v.x), eb = __expf(v.y);
        ehA[j] = ea; ehB[j] = eb; ShA += ea; ShB += eb;
    }
    const float invSwA = spanA / SwA, invSwB = spanB / SwB;
    const float invShA = spanA / ShA, invShB = spanB / ShB;

    // ---- fused cumsum + bin search + select (two independent chains: ILP) ----
    float cumxA = 0.f, cumyA = 0.f, cumxB = 0.f, cumyB = 0.f;
    float wA = ewA[0] * invSwA, hA = ehA[0] * invShA, xkA = 0.f, ykA = 0.f;
    float wB = ewB[0] * invSwB, hB = ehB[0] * invShB, xkB = 0.f, ykB = 0.f;
    int binA = 0, binB = 0;
#pragma unroll
    for (int j = 0; j < Kn; ++j) {
        const float wjA = ewA[j] * invSwA, hjA = ehA[j] * invShA;
        const float wjB = ewB[j] * invSwB, hjB = ehB[j] * invShB;
        if (xv2.x > x02.x + cumxA) { wA = wjA; hA = hjA; xkA = cumxA; ykA = cumyA; binA = j; }
        if (xv2.y > x02.y + cumxB) { wB = wjB; hB = hjB; xkB = cumxB; ykB = cumyB; binB = j; }
        cumxA += wjA; cumyA += hjA;
        cumxB += wjB; cumyB += hjB;
    }

    // ---- slope gathers at (bin, bin+1); lines mostly shared across lanes ----
    const float* ps = pb + (size_t)(2 * Kn) * Fn;
    const float s0A = ps[(size_t)binA * Fn + 2 * t];
    const float s1A = ps[(size_t)(binA + 1) * Fn + 2 * t];
    const float s0B = ps[(size_t)binB * Fn + 2 * t + 1];
    const float s1B = ps[(size_t)(binB + 1) * Fn + 2 * t + 1];

    // softplus(s) = max(s,0) + log1p(exp(-|s|))
    const float dkA  = fmaxf(s0A, 0.f) + log1pf(__expf(-fabsf(s0A)));
    const float dk1A = fmaxf(s1A, 0.f) + log1pf(__expf(-fabsf(s1A)));
    const float dkB  = fmaxf(s0B, 0.f) + log1pf(__expf(-fabsf(s0B)));
    const float dk1B = fmaxf(s1B, 0.f) + log1pf(__expf(-fabsf(s1B)));

    // ---- rational-quadratic spline, two features ----
    float2 y2;
    float dyA, dyB;
    {
        const float invw = 1.f / wA;
        const float s    = hA * invw;
        const float eps  = (xv2.x - (x02.x + xkA)) * invw;
        const float ome  = 1.f - eps;
        const float e1m  = eps * ome, e2 = eps * eps;
        const float den  = s + (dk1A + dkA - 2.f * s) * e1m;
        const float invd = 1.f / den;
        y2.x = (x02.x + ykA) + hA * (s * e2 + dkA * e1m) * invd;
        dyA  = s * s * (dk1A * e2 + 2.f * s * e1m + dkA * ome * ome) * (invd * invd);
    }
    {
        const float invw = 1.f / wB;
        const float s    = hB * invw;
        const float eps  = (xv2.y - (x02.y + xkB)) * invw;
        const float ome  = 1.f - eps;
        const float e1m  = eps * ome, e2 = eps * eps;
        const float den  = s + (dk1B + dkB - 2.f * s) * e1m;
        const float invd = 1.f / den;
        y2.y = (x02.y + ykB) + hB * (s * e2 + dkB * e1m) * invd;
        dyB  = s * s * (dk1B * e2 + 2.f * s * e1m + dkB * ome * ome) * (invd * invd);
    }

    ((float2*)(y_out + (size_t)b * Fn))[t] = y2;

    // ---- block reduction of log(dy) over 256 threads (4 waves) ----
    float ld = __logf(dyA * dyB);   // dy in a benign range; product safe in fp32
#pragma unroll
    for (int off = 32; off > 0; off >>= 1)
        ld += __shfl_down(ld, off, 64);

    __shared__ float wsum[4];
    const int lane = t & 63;
    const int wv   = t >> 6;
    if (lane == 0) wsum[wv] = ld;
    __syncthreads();
    if (t == 0)
        ld_out[b] = (wsum[0] + wsum[1]) + (wsum[2] + wsum[3]);
}

extern "C" void kernel_launch(void* const* d_in, const int* in_sizes, int n_in,
                              void* d_out, int out_size, void* d_ws, size_t ws_size,
                              hipStream_t stream) {
    const float* x   = (const float*)d_in[0];
    const float* prm = (const float*)d_in[1];
    const float* x0  = (const float*)d_in[2];
    const float* xf  = (const float*)d_in[3];
    float* y  = (float*)d_out;                  // (B, F) flat
    float* ld = y + (size_t)Bn * Fn;            // (B,) appended

    nsf_kernel<<<Bn, 256, 0, stream>>>(x, prm, x0, xf, y, ld);
}

// Round 4
// 61.163 us; speedup vs baseline: 1.2914x; 1.2652x over previous
//
#include <hip/hip_runtime.h>
#include <math.h>

// B=2048, F=512, K=32, P=3K+1=97
constexpr int Bn = 2048;
constexpr int Fn = 512;
constexpr int Kn = 32;
constexpr int Pn = 3 * Kn + 1;  // 97

// One block per batch row b (512 threads = 8 waves), one thread per feature f.
// R1 structure (best so far): dword coalesced loads for the 64 softmax rows,
// per-lane gathers for the 2 slope values (touches ~87% of slope lines).
// New: raw-cumsum bin search (scale once after the loop), fused/interleaved
// w+h load streams, nontemporal loads on the read-once softmax rows.
__global__ __launch_bounds__(Fn) void nsf_kernel(
    const float* __restrict__ x,
    const float* __restrict__ prm,
    const float* __restrict__ x0,
    const float* __restrict__ xf,
    float* __restrict__ y_out,
    float* __restrict__ ld_out)
{
    const int b = blockIdx.x;
    const int f = threadIdx.x;

    const float xv   = x[(size_t)b * Fn + f];
    const float x0v  = x0[f];
    const float span = xf[f] - x0v;

    const float* pb = prm + (size_t)b * Pn * Fn + f;

    // ---- fused width+height row loads (2 independent VMEM streams, nt) ----
    // no max-subtraction: logits ~N(0,1) -> exp in [e^-6, e^6], exact in fp32
    float ew[Kn], eh[Kn];
    float Sw = 0.f, Sh = 0.f;
#pragma unroll
    for (int j = 0; j < Kn; ++j) {
        const float lw = __builtin_nontemporal_load(pb + (size_t)j * Fn);
        const float lh = __builtin_nontemporal_load(pb + (size_t)(Kn + j) * Fn);
        const float a = __expf(lw);
        const float c = __expf(lh);
        ew[j] = a; eh[j] = c; Sw += a; Sh += c;
    }

    // ---- bin search on RAW cumulative exps (scale-invariant compare) ----
    // x > x0 + cum*span/Sw  <=>  (x-x0)*Sw/span > cum   (span, Sw > 0)
    const float T = (xv - x0v) * Sw / span;
    float cx = 0.f, cy = 0.f;
    float eb = ew[0], hb = eh[0], cxb = 0.f, cyb = 0.f;
    int bin = 0;
#pragma unroll
    for (int j = 0; j < Kn; ++j) {
        const bool c = (T > cx) || (j == 0);
        if (c) { eb = ew[j]; hb = eh[j]; cxb = cx; cyb = cy; bin = j; }
        cx += ew[j]; cy += eh[j];
    }

    // scale once after the loop
    const float invSw = span / Sw;
    const float invSh = span / Sh;
    const float w_b  = eb * invSw;
    const float h_b  = hb * invSh;
    const float xk_b = x0v + cxb * invSw;
    const float yk_b = x0v + cyb * invSh;

    // ---- slope gathers at (bin, bin+1); lines shared across lanes, cached ----
    const float* ps = pb + (size_t)(2 * Kn) * Fn;
    const float s0 = ps[(size_t)bin * Fn];
    const float s1 = ps[(size_t)(bin + 1) * Fn];

    // softplus(s) = max(s,0) + log1p(exp(-|s|))
    const float d_k  = fmaxf(s0, 0.f) + log1pf(__expf(-fabsf(s0)));
    const float d_k1 = fmaxf(s1, 0.f) + log1pf(__expf(-fabsf(s1)));

    // ---- rational-quadratic spline ----
    const float invw = 1.f / w_b;
    const float s    = h_b * invw;
    const float eps  = (xv - xk_b) * invw;
    const float ome  = 1.f - eps;
    const float e1m  = eps * ome;
    const float e2   = eps * eps;
    const float den  = s + (d_k1 + d_k - 2.f * s) * e1m;
    const float invd = 1.f / den;
    const float yv   = yk_b + h_b * (s * e2 + d_k * e1m) * invd;
    const float dy   = s * s * (d_k1 * e2 + 2.f * s * e1m + d_k * ome * ome) * (invd * invd);

    y_out[(size_t)b * Fn + f] = yv;

    // ---- block reduction of log(dy) over F=512 (8 waves) ----
    float ld = __logf(dy);
#pragma unroll
    for (int off = 32; off > 0; off >>= 1)
        ld += __shfl_down(ld, off, 64);

    __shared__ float wsum[Fn / 64];
    const int lane = f & 63;
    const int wv   = f >> 6;
    if (lane == 0) wsum[wv] = ld;
    __syncthreads();
    if (f == 0) {
        float t = 0.f;
#pragma unroll
        for (int i = 0; i < Fn / 64; ++i) t += wsum[i];
        ld_out[b] = t;
    }
}

extern "C" void kernel_launch(void* const* d_in, const int* in_sizes, int n_in,
                              void* d_out, int out_size, void* d_ws, size_t ws_size,
                              hipStream_t stream) {
    const float* x   = (const float*)d_in[0];
    const float* prm = (const float*)d_in[1];
    const float* x0  = (const float*)d_in[2];
    const float* xf  = (const float*)d_in[3];
    float* y  = (float*)d_out;                  // (B, F) flat
    float* ld = y + (size_t)Bn * Fn;            // (B,) appended

    nsf_kernel<<<Bn, Fn, 0, stream>>>(x, prm, x0, xf, y, ld);
}